// Round 8
// baseline (334.489 us; speedup 1.0000x reference)
//
#include <hip/hip_runtime.h>
#include <math.h>

#define NN 50000
#define NE 800000
#define NB 196        // dst buckets of 256 nodes
#define PBH 8192      // halfs per packed 64x64 W block: 2ks*2hl*4ct*64lane*8

typedef float v4f __attribute__((ext_vector_type(4)));
typedef float v2f __attribute__((ext_vector_type(2)));
typedef _Float16 v8h __attribute__((ext_vector_type(8)));

// ---------------- fp8 e4m3fn helpers: HW builtins w/ fallback ----------------
__device__ __forceinline__ unsigned char enc8(float v) {
#if __has_builtin(__builtin_amdgcn_cvt_pk_fp8_f32)
  return (unsigned char)(__builtin_amdgcn_cvt_pk_fp8_f32(v, v, 0, false) & 0xFF);
#else
  unsigned u = __float_as_uint(v);
  unsigned s = (u >> 24) & 0x80u;
  unsigned au = u & 0x7fffffffu;
  float a = __uint_as_float(au);
  if (au < 0x3C800000u) {
    int m = (int)(a * 512.0f + 0.5f);
    if (m >= 8) return (unsigned char)(s | 8u);
    return (unsigned char)(s | (unsigned)m);
  }
  unsigned r = au + 0x7FFFFu + ((au >> 20) & 1u);
  unsigned e = (r >> 23) - 120u;
  unsigned man = (r >> 20) & 7u;
  if (e > 15u) { e = 15u; man = 6u; }
  return (unsigned char)(s | (e << 3) | man);
#endif
}

#if __has_builtin(__builtin_amdgcn_cvt_pk_f32_fp8)
#define DEC8_HW 1
#else
__device__ __forceinline__ float dec8_1(unsigned b) {
  unsigned s = (b & 0x80u) << 24;
  unsigned em = b & 0x7fu;
  float v;
  if (em >= 8u) v = __uint_as_float((((em >> 3) + 120u) << 23) | ((em & 7u) << 20));
  else v = (float)em * 0.001953125f;
  return __uint_as_float(__float_as_uint(v) | s);
}
#endif

__device__ __forceinline__ void dec8x8(uint2 u, float* f) {
#ifdef DEC8_HW
  v2f p0 = __builtin_amdgcn_cvt_pk_f32_fp8((int)u.x, false);
  v2f p1 = __builtin_amdgcn_cvt_pk_f32_fp8((int)u.x, true);
  v2f p2 = __builtin_amdgcn_cvt_pk_f32_fp8((int)u.y, false);
  v2f p3 = __builtin_amdgcn_cvt_pk_f32_fp8((int)u.y, true);
  f[0] = p0.x; f[1] = p0.y; f[2] = p1.x; f[3] = p1.y;
  f[4] = p2.x; f[5] = p2.y; f[6] = p3.x; f[7] = p3.y;
#else
#pragma unroll
  for (int i = 0; i < 4; ++i) f[i] = dec8_1((u.x >> (8 * i)) & 0xFF);
#pragma unroll
  for (int i = 0; i < 4; ++i) f[4 + i] = dec8_1((u.y >> (8 * i)) & 0xFF);
#endif
}
__device__ __forceinline__ void dec8x16(uint4 u, float* f) {
  dec8x8(make_uint2(u.x, u.y), f);
  dec8x8(make_uint2(u.z, u.w), f + 8);
}

// ================= graph build (unchanged) ====================================

__global__ __launch_bounds__(256) void k_bhist(const int* __restrict__ dst,
                                               int* __restrict__ gbcnt) {
  __shared__ int lcnt[NB];
  int t = threadIdx.x;
  for (int i = t; i < NB; i += 256) lcnt[i] = 0;
  __syncthreads();
  int eb = blockIdx.x * 4096;
#pragma unroll
  for (int i = 0; i < 16; ++i) {
    int e = eb + i * 256 + t;
    if (e < NE) atomicAdd(&lcnt[dst[e] >> 8], 1);
  }
  __syncthreads();
  for (int i = t; i < NB; i += 256)
    if (lcnt[i]) atomicAdd(&gbcnt[i], lcnt[i]);
}

__global__ __launch_bounds__(256) void k_bscan(const int* __restrict__ gbcnt,
                                               int* __restrict__ boff,
                                               int* __restrict__ gcur,
                                               int* __restrict__ offs,
                                               float* __restrict__ sv) {
  __shared__ int sd[256];
  int t = threadIdx.x;
  sv[t] = 0.f;
  int v = (t < NB) ? gbcnt[t] : 0;
  sd[t] = v;
  __syncthreads();
  for (int o = 1; o < 256; o <<= 1) {
    int u = (t >= o) ? sd[t - o] : 0;
    __syncthreads();
    sd[t] += u;
    __syncthreads();
  }
  if (t < NB) { int x = sd[t] - v; boff[t] = x; gcur[t] = x; }
  if (t == NB - 1) boff[NB] = sd[t];
  if (t == 0) offs[NN] = NE;
}

__global__ __launch_bounds__(256) void k_bscatter(const int* __restrict__ src,
                                                  const int* __restrict__ dst,
                                                  int* __restrict__ gcur,
                                                  unsigned* __restrict__ ebuf) {
  __shared__ int cnt[NB];
  __shared__ int base[NB];
  int t = threadIdx.x;
  for (int i = t; i < NB; i += 256) cnt[i] = 0;
  __syncthreads();
  int eb = blockIdx.x * 4096;
  unsigned pk[16];
  int bk[16], lp[16];
#pragma unroll
  for (int i = 0; i < 16; ++i) {
    int e = eb + i * 256 + t;
    if (e < NE) {
      int d = dst[e];
      int b = d >> 8;
      pk[i] = ((unsigned)src[e] << 8) | (unsigned)(d & 255);
      bk[i] = b;
      lp[i] = atomicAdd(&cnt[b], 1);
    }
  }
  __syncthreads();
  for (int i = t; i < NB; i += 256)
    base[i] = cnt[i] ? atomicAdd(&gcur[i], cnt[i]) : 0;
  __syncthreads();
#pragma unroll
  for (int i = 0; i < 16; ++i) {
    int e = eb + i * 256 + t;
    if (e < NE) ebuf[base[bk[i]] + lp[i]] = pk[i];
  }
}

__global__ __launch_bounds__(256) void k_bbuild(const unsigned* __restrict__ ebuf,
                                                const int* __restrict__ boff,
                                                int* __restrict__ offs,
                                                float* __restrict__ invd,
                                                int* __restrict__ csr) {
  __shared__ int dcnt[256];
  __shared__ int cur[256];
  int t = threadIdx.x;
  int b = blockIdx.x;
  int node0 = b << 8;
  int es = boff[b], ee = boff[b + 1];
  dcnt[t] = 0;
  __syncthreads();
  for (int e = es + t; e < ee; e += 256) atomicAdd(&dcnt[ebuf[e] & 255], 1);
  __syncthreads();
  int v = dcnt[t];
  cur[t] = v;
  __syncthreads();
  for (int o = 1; o < 256; o <<= 1) {
    int u = (t >= o) ? cur[t - o] : 0;
    __syncthreads();
    cur[t] += u;
    __syncthreads();
  }
  int excl = cur[t] - v;
  int node = node0 + t;
  if (node < NN) {
    offs[node] = es + excl;
    invd[node] = 1.0f / fmaxf((float)v, 1.0f);
  }
  __syncthreads();
  cur[t] = es + excl;
  __syncthreads();
  for (int e = es + t; e < ee; e += 256) {
    unsigned pk = ebuf[e];
    int p = atomicAdd(&cur[pk & 255], 1);
    csr[p] = (int)(pk >> 8);
  }
}

// ================= weight pre-pack: fp32 [64][64] -> fragment-ordered =========
// packed[b][ks][hl][ct][lane][8] halfs; gate sigmoid folded in.
struct WPackArgs {
  const float* w[15];
  int gidx[15];
  const float* skip;
  _Float16* outp;
};

__global__ __launch_bounds__(256) void k_wpack(WPackArgs A) {
  __shared__ float sw[4096];
  int b = blockIdx.x, t = threadIdx.x;
  const float* w = A.w[b];
#pragma unroll
  for (int i = 0; i < 4; ++i)
    *(float4*)&sw[i * 1024 + t * 4] = *(const float4*)(w + i * 1024 + t * 4);
  float gs = 1.f;
  if (A.gidx[b] >= 0) gs = 1.f / (1.f + __expf(-A.skip[A.gidx[b]]));
  __syncthreads();
#pragma unroll
  for (int i = 0; i < 4; ++i) {
    int u = t * 4 + i;                  // u = ks*512 + hl*256 + ct*64 + lane
    int lane = u & 63, ct = (u >> 6) & 3, hl = (u >> 8) & 1, ks = (u >> 9) & 1;
    v8h val;
#pragma unroll
    for (int j = 0; j < 8; ++j) {
      int k = ks * 32 + ((lane >> 4) & 3) * 8 + j;
      int n = ct * 16 + (lane & 15);
      float f = sw[k * 64 + n] * gs;
      _Float16 h = (_Float16)f;
      val[j] = hl ? (_Float16)(f - (float)h) : h;
    }
    *(v8h*)(A.outp + (size_t)b * PBH + (size_t)u * 8) = val;
  }
}

// ========== fused gather/mean + multi-source linear (512 thr, K-split) ========
struct LinArgs {
  const _Float16* a[6];    // fp16 [n][64] row ptrs (a[fusedsrc] unused)
  int pb[6];               // packed W block indices
  int nsrc;
  int fusedsrc;
  const unsigned char* feat8;
  const int* offs;
  const int* csr;
  const float* invd;
  _Float16* mout;
  const _Float16* wp;      // packed weights base
  const float* bias;
  _Float16* outp;
  unsigned char* out8;
  float* colsum;
  int n;
  int relu;
};

__global__ __launch_bounds__(512) void k_linear(LinArgs A) {
  __shared__ _Float16 atile[64 * 72];   // 9216B; epilogue scratch after barrier
  __shared__ float cbuf[64 * 65];       // K-split combine, padded
  const int t    = threadIdx.x;
  const int lane = t & 63;
  const int w    = t >> 6;      // 0..7
  const int wq   = w & 3;       // row quadrant
  const int sg   = w >> 2;      // K-split group
  const int qd   = lane >> 4;
  const int ln   = lane & 15;
  const int n0   = blockIdx.x * 64;

  // ---------------- Phase A: gather (t = nd*8 + sl*4 + q) ----------------
  if (A.fusedsrc >= 0) {
    const int nd = t >> 3;
    const int sl = (t >> 2) & 1;
    const int q  = t & 3;
    const int node = n0 + nd;
    float a[16];
#pragma unroll
    for (int i = 0; i < 16; ++i) a[i] = 0.f;
    float dinv = 0.f;
    if (node < A.n) {
      int s = A.offs[node], e = A.offs[node + 1];
      dinv = A.invd[node];
      const unsigned char* fb = A.feat8;
      if (e > s) {
        int emax = e - 1;
        for (int p0 = s; p0 < e; p0 += 8) {
          int pa = p0 + sl, pb_ = p0 + 2 + sl, pc = p0 + 4 + sl, pd = p0 + 6 + sl;
          int ja = __builtin_nontemporal_load(A.csr + (pa < emax ? pa : emax));
          int jb = __builtin_nontemporal_load(A.csr + (pb_ < emax ? pb_ : emax));
          int jc = __builtin_nontemporal_load(A.csr + (pc < emax ? pc : emax));
          int jd = __builtin_nontemporal_load(A.csr + (pd < emax ? pd : emax));
          uint4 ua = *(const uint4*)(fb + (size_t)ja * 64 + q * 16);
          uint4 ub = *(const uint4*)(fb + (size_t)jb * 64 + q * 16);
          uint4 uc = *(const uint4*)(fb + (size_t)jc * 64 + q * 16);
          uint4 ud = *(const uint4*)(fb + (size_t)jd * 64 + q * 16);
          float f[16];
          dec8x16(ua, f);
          if (pa < e) {
#pragma unroll
            for (int i = 0; i < 16; ++i) a[i] += f[i];
          }
          dec8x16(ub, f);
          if (pb_ < e) {
#pragma unroll
            for (int i = 0; i < 16; ++i) a[i] += f[i];
          }
          dec8x16(uc, f);
          if (pc < e) {
#pragma unroll
            for (int i = 0; i < 16; ++i) a[i] += f[i];
          }
          dec8x16(ud, f);
          if (pd < e) {
#pragma unroll
            for (int i = 0; i < 16; ++i) a[i] += f[i];
          }
        }
      }
    }
#pragma unroll
    for (int i = 0; i < 16; ++i) a[i] += __shfl_xor(a[i], 4, 64);  // fold slots
    if (sl == 0) {
      v8h o0, o1;
#pragma unroll
      for (int i = 0; i < 8; ++i) {
        o0[i] = (_Float16)(a[i] * dinv);
        o1[i] = (_Float16)(a[8 + i] * dinv);
      }
      *(v8h*)(&atile[nd * 72 + q * 16]) = o0;
      *(v8h*)(&atile[nd * 72 + q * 16 + 8]) = o1;
      if (A.mout && node < A.n) {
        *(v8h*)(A.mout + (size_t)node * 64 + q * 16) = o0;
        *(v8h*)(A.mout + (size_t)node * 64 + q * 16 + 8) = o1;
      }
    }
  }
  __syncthreads();

  // ---------------- Phase B: MFMA, sources split across wave groups -----------
  v4f acc[4];
#pragma unroll
  for (int ct = 0; ct < 4; ++ct) acc[ct] = (v4f){0.f, 0.f, 0.f, 0.f};

  const int arow = n0 + wq * 16 + ln;
  const bool arv = arow < A.n;
  const int h = (A.nsrc + 1) >> 1;
  const int sbeg = sg ? h : 0;
  const int send = sg ? A.nsrc : h;
  v8h ah[2];

  for (int s = sbeg; s < send; ++s) {
    if (s == A.fusedsrc) {
      const _Float16* ph = atile + (wq * 16 + ln) * 72;
      ah[0] = *(const v8h*)(ph + qd * 8);
      ah[1] = *(const v8h*)(ph + 32 + qd * 8);
    } else if (arv) {
      const _Float16* ph = A.a[s] + (size_t)arow * 64;
      ah[0] = *(const v8h*)(ph + qd * 8);
      ah[1] = *(const v8h*)(ph + 32 + qd * 8);
    } else {
      v8h z;
#pragma unroll
      for (int j = 0; j < 8; ++j) z[j] = (_Float16)0.f;
      ah[0] = ah[1] = z;
    }
    const _Float16* pw = A.wp + (size_t)A.pb[s] * PBH;
#pragma unroll
    for (int ks = 0; ks < 2; ++ks) {
#pragma unroll
      for (int ct = 0; ct < 4; ++ct) {
        const _Float16* pf = pw + (size_t)(ks * 512 + ct * 64 + lane) * 8;
        v8h bh = *(const v8h*)(pf);
        v8h bl = *(const v8h*)(pf + 256 * 8);
        acc[ct] = __builtin_amdgcn_mfma_f32_16x16x32_f16(ah[ks], bh, acc[ct], 0, 0, 0);
        acc[ct] = __builtin_amdgcn_mfma_f32_16x16x32_f16(ah[ks], bl, acc[ct], 0, 0, 0);
      }
    }
  }

  // K-split combine: sg1 deposits, sg0 adds
  if (sg == 1) {
#pragma unroll
    for (int ct = 0; ct < 4; ++ct)
#pragma unroll
      for (int r = 0; r < 4; ++r) {
        int nb = wq * 16 + qd * 4 + r;
        cbuf[nb * 65 + ct * 16 + ln] = acc[ct][r];
      }
  }
  __syncthreads();

  unsigned char* f8t = (unsigned char*)atile;       // 4KB
  float* red = (float*)&atile[2304];                 // 1KB at byte 4608

  if (sg == 0) {
    float bvals[4];
#pragma unroll
    for (int ct = 0; ct < 4; ++ct) bvals[ct] = A.bias[ct * 16 + ln];
    float cs[4] = {0.f, 0.f, 0.f, 0.f};
#pragma unroll
    for (int ct = 0; ct < 4; ++ct) {
#pragma unroll
      for (int r = 0; r < 4; ++r) {
        int nb = wq * 16 + qd * 4 + r;
        int node = n0 + nb;
        float v = acc[ct][r] + cbuf[nb * 65 + ct * 16 + ln] + bvals[ct];
        if (A.relu) v = fmaxf(v, 0.f);
        if (node < A.n) {
          if (A.outp) A.outp[(size_t)node * 64 + ct * 16 + ln] = (_Float16)v;
          if (A.out8) f8t[nb * 64 + ct * 16 + ln] = enc8(v);
          cs[ct] += v;
        }
      }
    }
    if (A.colsum) {
#pragma unroll
      for (int ct = 0; ct < 4; ++ct) {
        float v = cs[ct];
        v += __shfl_xor(v, 16, 64);
        v += __shfl_xor(v, 32, 64);
        if (qd == 0) red[wq * 64 + ct * 16 + ln] = v;
      }
    }
  }
  if (A.out8 || A.colsum) __syncthreads();
  if (A.out8 && t < 256) {
    int row = t >> 2, ch = t & 3;
    if (n0 + row < A.n) {
      uint4 val = *(const uint4*)(f8t + row * 64 + ch * 16);
      *(uint4*)(A.out8 + (size_t)(n0 + row) * 64 + ch * 16) = val;
    }
  }
  if (A.colsum && t < 64) {
    float ssum = red[t] + red[64 + t] + red[128 + t] + red[192 + t];
    atomicAdd(&A.colsum[t], ssum);
  }
}

// ============== fused pre-MLP with packed weights (blocks 0,1,2) ==============
__global__ __launch_bounds__(256) void k_pre(
    const float* __restrict__ nf, const _Float16* __restrict__ wp,
    const float* __restrict__ b1, const float* __restrict__ b2,
    _Float16* __restrict__ xout, unsigned char* __restrict__ x8,
    float* __restrict__ colsum, int n) {
  __shared__ _Float16 atile[64 * 72];
  const int t    = threadIdx.x;
  const int lane = t & 63;
  const int wv   = t >> 6;
  const int qd   = lane >> 4;
  const int ln   = lane & 15;
  const int n0   = blockIdx.x * 64;
  const int arow = n0 + wv * 16 + ln;
  const bool arv = arow < n;

  v4f acc[4];
#pragma unroll
  for (int ct = 0; ct < 4; ++ct) acc[ct] = (v4f){0.f, 0.f, 0.f, 0.f};
  v8h ah[2];

  auto domfma = [&](int pbi) {
    const _Float16* pw = wp + (size_t)pbi * PBH;
#pragma unroll
    for (int ks = 0; ks < 2; ++ks) {
#pragma unroll
      for (int ct = 0; ct < 4; ++ct) {
        const _Float16* pf = pw + (size_t)(ks * 512 + ct * 64 + lane) * 8;
        v8h bh = *(const v8h*)(pf);
        v8h bl = *(const v8h*)(pf + 256 * 8);
        acc[ct] = __builtin_amdgcn_mfma_f32_16x16x32_f16(ah[ks], bh, acc[ct], 0, 0, 0);
        acc[ct] = __builtin_amdgcn_mfma_f32_16x16x32_f16(ah[ks], bl, acc[ct], 0, 0, 0);
      }
    }
  };

  // stage 1: t0 = relu(nf@W1 + b1); K=128 as two 64-col sources (pb 0,1)
  for (int s = 0; s < 2; ++s) {
#pragma unroll
    for (int ks = 0; ks < 2; ++ks) {
      v8h hv;
      if (arv) {
        const float* p = nf + (size_t)arow * 128 + s * 64 + ks * 32 + qd * 8;
        float4 u0 = *(const float4*)(p);
        float4 u1 = *(const float4*)(p + 4);
        hv[0] = (_Float16)u0.x; hv[1] = (_Float16)u0.y;
        hv[2] = (_Float16)u0.z; hv[3] = (_Float16)u0.w;
        hv[4] = (_Float16)u1.x; hv[5] = (_Float16)u1.y;
        hv[6] = (_Float16)u1.z; hv[7] = (_Float16)u1.w;
      } else {
#pragma unroll
        for (int j = 0; j < 8; ++j) hv[j] = (_Float16)0.f;
      }
      ah[ks] = hv;
    }
    domfma(s);
  }

  float b1v[4];
#pragma unroll
  for (int ct = 0; ct < 4; ++ct) b1v[ct] = b1[ct * 16 + ln];
#pragma unroll
  for (int ct = 0; ct < 4; ++ct) {
#pragma unroll
    for (int r = 0; r < 4; ++r) {
      int nb = wv * 16 + qd * 4 + r;
      float v = fmaxf(acc[ct][r] + b1v[ct], 0.f);
      atile[nb * 72 + ct * 16 + ln] = (_Float16)v;
    }
  }
#pragma unroll
  for (int ct = 0; ct < 4; ++ct) acc[ct] = (v4f){0.f, 0.f, 0.f, 0.f};
  __syncthreads();

  // stage 2: x = t0 @ W2 + b2  (pb 2)
  {
    const _Float16* ph = atile + (wv * 16 + ln) * 72;
    ah[0] = *(const v8h*)(ph + qd * 8);
    ah[1] = *(const v8h*)(ph + 32 + qd * 8);
  }
  domfma(2);

  float b2v[4];
#pragma unroll
  for (int ct = 0; ct < 4; ++ct) b2v[ct] = b2[ct * 16 + ln];

  __syncthreads();   // all atile fragment reads complete; reuse as scratch
  unsigned char* f8t = (unsigned char*)atile;
  float* red = (float*)&atile[2304];
  float cs[4] = {0.f, 0.f, 0.f, 0.f};
#pragma unroll
  for (int ct = 0; ct < 4; ++ct) {
#pragma unroll
    for (int r = 0; r < 4; ++r) {
      int nb = wv * 16 + qd * 4 + r;
      int node = n0 + nb;
      float v = acc[ct][r] + b2v[ct];
      if (node < n) {
        xout[(size_t)node * 64 + ct * 16 + ln] = (_Float16)v;
        f8t[nb * 64 + ct * 16 + ln] = enc8(v);
        cs[ct] += v;
      }
    }
  }
#pragma unroll
  for (int ct = 0; ct < 4; ++ct) {
    float v = cs[ct];
    v += __shfl_xor(v, 16, 64);
    v += __shfl_xor(v, 32, 64);
    if (qd == 0) red[wv * 64 + ct * 16 + ln] = v;
  }
  __syncthreads();
  {
    int row = t >> 2, ch = t & 3;
    if (n0 + row < n) {
      uint4 val = *(const uint4*)(f8t + row * 64 + ch * 16);
      *(uint4*)(x8 + (size_t)(n0 + row) * 64 + ch * 16) = val;
    }
  }
  if (t < 64) {
    float ssum = red[t] + red[64 + t] + red[128 + t] + red[192 + t];
    atomicAdd(&colsum[t], ssum);
  }
}

// ---------------- tiny post-MLP (single block) ----------------
__global__ __launch_bounds__(256) void k_post(const float* __restrict__ s,
                                              const float* __restrict__ w1, const float* __restrict__ b1,
                                              const float* __restrict__ w2, const float* __restrict__ b2,
                                              const float* __restrict__ w3, const float* __restrict__ b3,
                                              const float* __restrict__ w4, const float* __restrict__ b4,
                                              float* __restrict__ outp) {
  __shared__ float sh[256], h1[64], h2[64], h3[256];
  int t = threadIdx.x;
  sh[t] = s[t];
  __syncthreads();
  if (t < 64) {
    float a = b1[t];
    for (int k = 0; k < 256; ++k) a += sh[k] * w1[k * 64 + t];
    h1[t] = (a >= 0.f) ? a : 0.1f * a;
  }
  __syncthreads();
  if (t < 64) {
    float a = b2[t];
    for (int k = 0; k < 64; ++k) a += h1[k] * w2[k * 64 + t];
    h2[t] = fmaxf(a, 0.f);
  }
  __syncthreads();
  {
    float a = b3[t];
    for (int k = 0; k < 64; ++k) a += h2[k] * w3[k * 256 + t];
    h3[t] = fmaxf(a, 0.f);
  }
  __syncthreads();
  if (t < 64) {
    float a = b4[t];
    for (int k = 0; k < 256; ++k) a += h3[k] * w4[k * 64 + t];
    outp[t] = a;
  }
}

extern "C" void kernel_launch(void* const* d_in, const int* in_sizes, int n_in,
                              void* d_out, int out_size, void* d_ws, size_t ws_size,
                              hipStream_t stream) {
  const float* nf     = (const float*)d_in[0];
  const int*   ei     = (const int*)d_in[1];
  const float* pre_w1 = (const float*)d_in[2];
  const float* pre_b1 = (const float*)d_in[3];
  const float* pre_w2 = (const float*)d_in[4];
  const float* pre_b2 = (const float*)d_in[5];
  const float* skip   = (const float*)d_in[6];
  const float* wl0 = (const float*)d_in[7],  *bl0 = (const float*)d_in[8],  *wr0 = (const float*)d_in[9];
  const float* wl1 = (const float*)d_in[10], *bl1 = (const float*)d_in[11], *wr1 = (const float*)d_in[12];
  const float* wl2 = (const float*)d_in[13], *bl2 = (const float*)d_in[14], *wr2 = (const float*)d_in[15];
  const float* pw1 = (const float*)d_in[16], *pb1 = (const float*)d_in[17];
  const float* pw2 = (const float*)d_in[18], *pb2 = (const float*)d_in[19];
  const float* pw3 = (const float*)d_in[20], *pb3 = (const float*)d_in[21];
  const float* pw4 = (const float*)d_in[22], *pb4 = (const float*)d_in[23];
  float* out = (float*)d_out;

  const int N = NN, E = NE;

  char* ws = (char*)d_ws;
  size_t pos = 0;
  auto alloc = [&](size_t bytes) {
    char* p = ws + pos;
    pos += (bytes + 255) & ~(size_t)255;
    return (void*)p;
  };
  int*      gbcnt = (int*)alloc((size_t)NB * 4);
  int*      boff  = (int*)alloc((size_t)(NB + 1) * 4);
  int*      gcur  = (int*)alloc((size_t)NB * 4);
  unsigned* ebuf  = (unsigned*)alloc((size_t)E * 4);
  int*      offs  = (int*)alloc((size_t)(N + 1) * 4);
  float*    invd  = (float*)alloc((size_t)N * 4);
  int*      csr   = (int*)alloc((size_t)E * 4);
  const size_t PB = (size_t)N * 64 * 2;
  _Float16* x  = (_Float16*)alloc(PB);
  _Float16* h0 = (_Float16*)alloc(PB);
  _Float16* h1 = (_Float16*)alloc(PB);
  _Float16* m0 = (_Float16*)alloc(PB);
  _Float16* m1 = (_Float16*)alloc(PB);
  unsigned char* f8 = (unsigned char*)alloc((size_t)N * 64);
  _Float16* wpk = (_Float16*)alloc((size_t)15 * PBH * 2);
  float* sv = (float*)alloc(256 * 4);

  hipMemsetAsync(gbcnt, 0, (size_t)NB * 4, stream);

  // weight pre-pack (15 blocks; gates folded)
  {
    WPackArgs W;
    const float* wsrc[15] = {pre_w1, pre_w1 + 64 * 64, pre_w2,
                             wl0, wr0,
                             wl1, wl1 + 64 * 64, wr1, wr1 + 64 * 64,
                             wl2, wl2 + 64 * 64, wl2 + 128 * 64,
                             wr2, wr2 + 64 * 64, wr2 + 128 * 64};
    const int gi[15] = {-1, -1, -1, 0, 0, 3, 4, 3, 4, 6, 7, 8, 6, 7, 8};
    for (int i = 0; i < 15; ++i) { W.w[i] = wsrc[i]; W.gidx[i] = gi[i]; }
    W.skip = skip; W.outp = wpk;
    k_wpack<<<15, 256, 0, stream>>>(W);
  }

  const int* e_src = ei;
  const int* e_dst = ei + E;
  const int EGRID = (E + 4095) / 4096;
  k_bhist<<<EGRID, 256, 0, stream>>>(e_dst, gbcnt);
  k_bscan<<<1, 256, 0, stream>>>(gbcnt, boff, gcur, offs, sv);
  k_bscatter<<<EGRID, 256, 0, stream>>>(e_src, e_dst, gcur, ebuf);
  k_bbuild<<<NB, 256, 0, stream>>>(ebuf, boff, offs, invd, csr);

  const int LGRID = (N + 63) / 64;   // 782
  auto lin = [&](int nsrc, int fusedsrc, _Float16* mout,
                 const _Float16* a0, int p0, const _Float16* a1, int p1,
                 const _Float16* a2, int p2, const _Float16* a3, int p3,
                 const _Float16* a4, int p4, const _Float16* a5, int p5,
                 const float* bias, _Float16* op, unsigned char* o8,
                 float* colsum, int relu) {
    LinArgs A;
    A.a[0] = a0; A.a[1] = a1; A.a[2] = a2; A.a[3] = a3; A.a[4] = a4; A.a[5] = a5;
    A.pb[0] = p0; A.pb[1] = p1; A.pb[2] = p2; A.pb[3] = p3; A.pb[4] = p4; A.pb[5] = p5;
    A.nsrc = nsrc; A.fusedsrc = fusedsrc;
    A.feat8 = f8; A.offs = offs; A.csr = csr; A.invd = invd;
    A.mout = mout; A.wp = wpk;
    A.bias = bias; A.outp = op; A.out8 = o8; A.colsum = colsum;
    A.n = N; A.relu = relu;
    k_linear<<<LGRID, 512, 0, stream>>>(A);
  };

  // fused pre-MLP: x (fp16 + fp8) + colsum sv[0:64]
  k_pre<<<LGRID, 256, 0, stream>>>(nf, wpk, pre_b1, pre_b2, x, f8, sv, N);

  // layer 0: sg0={fused agg->m0 @wl0}, sg1={x @wr0}
  lin(2, 0, m0,
      nullptr, 3, x, 4,
      nullptr, 0, nullptr, 0, nullptr, 0, nullptr, 0,
      bl0, h0, f8, sv + 64, 1);

  // layer 1: sg0={m0@wl1[0], fused->m1 @wl1[1]}, sg1={x@wr1[0], h0@wr1[1]}
  lin(4, 1, m1,
      m0, 5, nullptr, 6, x, 7, h0, 8,
      nullptr, 0, nullptr, 0,
      bl1, h1, f8, sv + 128, 1);

  // layer 2: sg0={m0,m1,fused(m2)}@wl2 blocks, sg1={x,h0,h1}@wr2 blocks
  lin(6, 2, nullptr,
      m0, 9, m1, 10, nullptr, 11, x, 12, h0, 13, h1, 14,
      bl2, nullptr, nullptr, sv + 192, 1);

  k_post<<<1, 256, 0, stream>>>(sv, pw1, pb1, pw2, pb2, pw3, pb3, pw4, pb4, out);
}